// Round 4
// baseline (101851.703 us; speedup 1.0000x reference)
//
#include <hip/hip_runtime.h>
#include <hip/hip_cooperative_groups.h>

namespace cg = cooperative_groups;

// Problem constants (match reference)
constexpr int Bsz  = 256;   // batch
constexpr int Lf   = 14;    // input features
constexpr int Tt   = 500;   // timesteps
constexpr int Hn   = 1000;  // hidden per layer
constexpr int HT   = 4;     // h-rows per block
constexpr int NBLK = Hn / HT;   // 250 blocks
constexpr int KPAD = 1024;      // spike row stride in bytes
constexpr int NKS  = 4;         // k-splits (block = NKS * 256 threads)

// Dynamic LDS layout (floats):
//   [0, 20000)      5 weight matrices x 4 rows x 1000 k   (R1,W2,R2,W3,R3)
//   [20000, 20056)  W1 rows (4 x 14)
//   [20056, ...)    red[3][NKS-1][256] float4 partial sums (36864 B)
constexpr int LDSW_F   = 5 * HT * Hn;        // 20000
constexpr int LDSW1_F  = HT * Lf;            // 56
constexpr int RED_OFF  = LDSW_F + LDSW1_F;   // 20056 floats (byte off 80224, 16B-aligned)
constexpr size_t SMEM_BYTES = (size_t)RED_OFF * 4 + (size_t)3 * (NKS - 1) * Bsz * 16; // 117088

// Spike byte buffers in d_ws: [slot:2][layer:3][b:256][KPAD] u8 (1.5 MB)
__device__ __forceinline__ size_t srow_off(int slot, int layer, int b) {
  return (((size_t)slot * 3 + layer) * Bsz + b) * KPAD;
}

// 4 bytes of a dword -> 4 floats (0.0/1.0); selects v_cvt_f32_ubyte0..3
__device__ __forceinline__ void cvt4(unsigned w, float* s) {
  s[0] = (float)(w & 0xffu);
  s[1] = (float)((w >> 8) & 0xffu);
  s[2] = (float)((w >> 16) & 0xffu);
  s[3] = (float)(w >> 24);
}

// acc[j] += sum_{k in [k0,k1)} spike(b,k) * lw[j*Hn + k]
// srow: per-lane global spike row. lw: LDS weight base (wave-uniform reads).
__device__ __forceinline__ void accum_range_lds(float acc[HT],
    const unsigned char* __restrict__ srow,
    const float* lw, int k0, int k1) {
  int kc = k0;
  for (; kc + 16 <= k1; kc += 16) {
    uint4 sw = *(const uint4*)(srow + kc);
    float s[16];
    cvt4(sw.x, s); cvt4(sw.y, s + 4); cvt4(sw.z, s + 8); cvt4(sw.w, s + 12);
#pragma unroll
    for (int j = 0; j < HT; ++j) {
      const float* wr = lw + j * Hn + kc;
      float4 wa = *(const float4*)(wr);
      float4 wb = *(const float4*)(wr + 4);
      float4 wc = *(const float4*)(wr + 8);
      float4 wd = *(const float4*)(wr + 12);
      acc[j] = fmaf(wa.x, s[0],  acc[j]);
      acc[j] = fmaf(wa.y, s[1],  acc[j]);
      acc[j] = fmaf(wa.z, s[2],  acc[j]);
      acc[j] = fmaf(wa.w, s[3],  acc[j]);
      acc[j] = fmaf(wb.x, s[4],  acc[j]);
      acc[j] = fmaf(wb.y, s[5],  acc[j]);
      acc[j] = fmaf(wb.z, s[6],  acc[j]);
      acc[j] = fmaf(wb.w, s[7],  acc[j]);
      acc[j] = fmaf(wc.x, s[8],  acc[j]);
      acc[j] = fmaf(wc.y, s[9],  acc[j]);
      acc[j] = fmaf(wc.z, s[10], acc[j]);
      acc[j] = fmaf(wc.w, s[11], acc[j]);
      acc[j] = fmaf(wd.x, s[12], acc[j]);
      acc[j] = fmaf(wd.y, s[13], acc[j]);
      acc[j] = fmaf(wd.z, s[14], acc[j]);
      acc[j] = fmaf(wd.w, s[15], acc[j]);
    }
  }
  if (kc < k1) {  // 8-wide tail (k-range 232 for ks==3)
    uint2 sw = *(const uint2*)(srow + kc);
    float s[8];
    cvt4(sw.x, s); cvt4(sw.y, s + 4);
#pragma unroll
    for (int j = 0; j < HT; ++j) {
      const float* wr = lw + j * Hn + kc;
      float4 wa = *(const float4*)(wr);
      float4 wb = *(const float4*)(wr + 4);
      acc[j] = fmaf(wa.x, s[0], acc[j]);
      acc[j] = fmaf(wa.y, s[1], acc[j]);
      acc[j] = fmaf(wa.z, s[2], acc[j]);
      acc[j] = fmaf(wa.w, s[3], acc[j]);
      acc[j] = fmaf(wb.x, s[4], acc[j]);
      acc[j] = fmaf(wb.y, s[5], acc[j]);
      acc[j] = fmaf(wb.z, s[6], acc[j]);
      acc[j] = fmaf(wb.w, s[7], acc[j]);
    }
  }
}

// LIF (tau=2, v_th=1, hard reset) for 4 neurons; returns packed spike bytes
__device__ __forceinline__ unsigned lif_pack(float v[HT], const float a[HT]) {
  unsigned pack = 0;
#pragma unroll
  for (int j = 0; j < HT; ++j) {
    float vn = v[j] + (a[j] - v[j]) * 0.5f;
    bool sp = (vn >= 1.0f);
    v[j] = sp ? 0.0f : vn;
    pack |= (sp ? 1u : 0u) << (8 * j);
  }
  return pack;
}

__global__ void __launch_bounds__(1024, 4)
snn_coop(const float* __restrict__ x,
         const float* __restrict__ W1, const float* __restrict__ R1,
         const float* __restrict__ W2, const float* __restrict__ R2,
         const float* __restrict__ W3, const float* __restrict__ R3,
         unsigned char* __restrict__ sb,
         float* __restrict__ out)
{
  cg::grid_group grid = cg::this_grid();
  extern __shared__ float smem[];
  float* lds_w  = smem;                       // 5 x [HT][Hn]
  float* lds_w1 = smem + LDSW_F;              // [HT][Lf]
  float4* red   = (float4*)(smem + RED_OFF);  // [3][NKS-1][Bsz]

  const int tid = threadIdx.x;
  const int b   = tid & 255;                                  // batch
  const int ks  = __builtin_amdgcn_readfirstlane(tid >> 8);   // k-split 0..3
  const int h0  = blockIdx.x * HT;                            // uniform

  const int k0 = ks * 256;
  const int k1 = (ks == 3) ? Hn : (k0 + 256);   // 256/256/256/232

  // ---- stage this block's weights into LDS (once) ----
  {
    const float* mats[5] = { R1 + (size_t)h0 * Hn, W2 + (size_t)h0 * Hn,
                             R2 + (size_t)h0 * Hn, W3 + (size_t)h0 * Hn,
                             R3 + (size_t)h0 * Hn };
#pragma unroll
    for (int m = 0; m < 5; ++m) {
      const float4* src = (const float4*)mats[m];   // 1000 float4 (rows contiguous)
      float4* dst = (float4*)(lds_w + m * (HT * Hn));
      if (tid < 1000) dst[tid] = src[tid];
    }
    if (tid < LDSW1_F) lds_w1[tid] = (W1 + (size_t)h0 * Lf)[tid];
  }
  __syncthreads();

  const float* lR1 = lds_w;
  const float* lW2 = lds_w + 1 * (HT * Hn);
  const float* lR2 = lds_w + 2 * (HT * Hn);
  const float* lW3 = lds_w + 3 * (HT * Hn);
  const float* lR3 = lds_w + 4 * (HT * Hn);

  float v1[HT], v2[HT], v3[HT];
#pragma unroll
  for (int j = 0; j < HT; ++j) { v1[j] = 0.f; v2[j] = 0.f; v3[j] = 0.f; }

  const float* xb = x + (size_t)b * (Lf * Tt); // x[b][l][t]

  // Diagonal pipeline: phase p -> L1@t=p, L2@t=p-1, L3@t=p-2.
  // Spike writes in phase p go to slot (p&1); reads from slot ((p-1)&1).
  for (int p = 0; p < Tt + 2; ++p) {
    const int srd = (p + 1) & 1;
    const int swr = p & 1;

    float a1[HT] = {0.f, 0.f, 0.f, 0.f};
    float a2[HT] = {0.f, 0.f, 0.f, 0.f};
    float a3[HT] = {0.f, 0.f, 0.f, 0.f};

    const bool l1on = (p < Tt);
    const bool l2on = (p >= 1) && (p <= Tt);
    const bool l3on = (p >= 2);

    if (l1on) {
      if (ks == 3) {   // feedforward x @ W1^T (k=14) on the lighter k-split
#pragma unroll
        for (int l = 0; l < Lf; ++l) {
          float xv = xb[(size_t)l * Tt + p];
#pragma unroll
          for (int j = 0; j < HT; ++j)
            a1[j] = fmaf(lds_w1[j * Lf + l], xv, a1[j]);
        }
      }
      accum_range_lds(a1, sb + srow_off(srd, 0, b), lR1, k0, k1);  // c1 @ R1^T
    }
    if (l2on) {
      accum_range_lds(a2, sb + srow_off(srd, 0, b), lW2, k0, k1);  // s1 @ W2^T
      accum_range_lds(a2, sb + srow_off(srd, 1, b), lR2, k0, k1);  // c2 @ R2^T
    }
    if (l3on) {
      accum_range_lds(a3, sb + srow_off(srd, 1, b), lW3, k0, k1);  // s2 @ W3^T
      accum_range_lds(a3, sb + srow_off(srd, 2, b), lR3, k0, k1);  // c3 @ R3^T
    }

    if (ks != 0) {
      if (l1on) red[(0 * (NKS - 1) + ks - 1) * Bsz + b] = make_float4(a1[0], a1[1], a1[2], a1[3]);
      if (l2on) red[(1 * (NKS - 1) + ks - 1) * Bsz + b] = make_float4(a2[0], a2[1], a2[2], a2[3]);
      if (l3on) red[(2 * (NKS - 1) + ks - 1) * Bsz + b] = make_float4(a3[0], a3[1], a3[2], a3[3]);
    }
    __syncthreads();

    if (ks == 0) {
      if (l1on) {
#pragma unroll
        for (int q = 0; q < NKS - 1; ++q) {
          float4 r = red[(0 * (NKS - 1) + q) * Bsz + b];
          a1[0] += r.x; a1[1] += r.y; a1[2] += r.z; a1[3] += r.w;
        }
        *(unsigned*)(sb + srow_off(swr, 0, b) + h0) = lif_pack(v1, a1);
      }
      if (l2on) {
#pragma unroll
        for (int q = 0; q < NKS - 1; ++q) {
          float4 r = red[(1 * (NKS - 1) + q) * Bsz + b];
          a2[0] += r.x; a2[1] += r.y; a2[2] += r.z; a2[3] += r.w;
        }
        *(unsigned*)(sb + srow_off(swr, 1, b) + h0) = lif_pack(v2, a2);
      }
      if (l3on) {
#pragma unroll
        for (int q = 0; q < NKS - 1; ++q) {
          float4 r = red[(2 * (NKS - 1) + q) * Bsz + b];
          a3[0] += r.x; a3[1] += r.y; a3[2] += r.z; a3[3] += r.w;
        }
        *(unsigned*)(sb + srow_off(swr, 2, b) + h0) = lif_pack(v3, a3);
      }
    }

    __threadfence();   // spike stores visible device-wide before next phase
    grid.sync();       // also orders red[] reads vs next phase's writes
  }

  // Output: exp(final v3); [B][H] row-major, float4 store
  if (ks == 0) {
    float4 o = make_float4(expf(v3[0]), expf(v3[1]), expf(v3[2]), expf(v3[3]));
    *(float4*)(out + (size_t)b * Hn + h0) = o;
  }
}

extern "C" void kernel_launch(void* const* d_in, const int* in_sizes, int n_in,
                              void* d_out, int out_size, void* d_ws, size_t ws_size,
                              hipStream_t stream) {
  const float* x  = (const float*)d_in[0];
  const float* W1 = (const float*)d_in[1];
  const float* R1 = (const float*)d_in[2];
  const float* W2 = (const float*)d_in[3];
  const float* R2 = (const float*)d_in[4];
  const float* W3 = (const float*)d_in[5];
  const float* R3 = (const float*)d_in[6];
  float* out = (float*)d_out;

  unsigned char* sbytes = (unsigned char*)d_ws;
  const size_t sb_bytes = (size_t)2 * 3 * Bsz * KPAD; // 1,572,864 B

  // allow >64KB dynamic LDS (host-side attribute set; graph-capture safe)
  hipFuncSetAttribute((const void*)snn_coop,
                      hipFuncAttributeMaxDynamicSharedMemorySize,
                      (int)SMEM_BYTES);

  // zero both spike slots (initial carries are zero)
  hipMemsetAsync(d_ws, 0, sb_bytes, stream);

  void* args[] = { (void*)&x, (void*)&W1, (void*)&R1, (void*)&W2, (void*)&R2,
                   (void*)&W3, (void*)&R3, (void*)&sbytes, (void*)&out };
  hipLaunchCooperativeKernel((const void*)snn_coop, dim3(NBLK), dim3(1024),
                             args, SMEM_BYTES, stream);
}

// Round 5
// 56166.779 us; speedup vs baseline: 1.8134x; 1.8134x over previous
//
#include <hip/hip_runtime.h>

// Problem constants (match reference)
constexpr int Bsz  = 256;   // batch
constexpr int Lf   = 14;    // input features
constexpr int Tt   = 500;   // timesteps
constexpr int Hn   = 1000;  // hidden per layer
constexpr int HT   = 4;     // h-rows per block
constexpr int NBLK = Hn / HT;   // 250 blocks
constexpr int KPAD = 1024;      // spike row stride in bytes
constexpr int NKS  = 4;         // k-splits (block = NKS * 256 threads)

// d_ws layout: [0, SB_BYTES) spike bytes [slot:2][layer:3][b:256][KPAD]
//              [SB_BYTES, +4) barrier counter
constexpr size_t SB_BYTES = (size_t)2 * 3 * Bsz * KPAD; // 1,572,864

// LDS: red[3][NKS-1][Bsz] float4 = 36,864 B; request padded to force 1 block/CU
constexpr size_t RED_BYTES  = (size_t)3 * (NKS - 1) * Bsz * 16;
constexpr size_t SMEM_BYTES = 98304;  // 96 KB -> 2 blocks would exceed 160 KB/CU

using u32x4 = __attribute__((ext_vector_type(4))) unsigned int;
using u32x2 = __attribute__((ext_vector_type(2))) unsigned int;

__device__ __forceinline__ size_t srow_off(int slot, int layer, int b) {
  return (((size_t)slot * 3 + layer) * Bsz + b) * KPAD;
}

// 4 bytes of a dword -> 4 floats (0.0/1.0); selects v_cvt_f32_ubyte0..3
__device__ __forceinline__ void cvt4(unsigned w, float* s) {
  s[0] = (float)(w & 0xffu);
  s[1] = (float)((w >> 8) & 0xffu);
  s[2] = (float)((w >> 16) & 0xffu);
  s[3] = (float)(w >> 24);
}

// 64 spike bytes via coherent (L2-bypassing) loads; waits its own vmcnt.
__device__ __forceinline__ void spk_load64(const unsigned char* p, u32x4 sp[4]) {
  asm volatile(
      "global_load_dwordx4 %0, %4, off sc0 sc1\n\t"
      "global_load_dwordx4 %1, %4, off offset:16 sc0 sc1\n\t"
      "global_load_dwordx4 %2, %4, off offset:32 sc0 sc1\n\t"
      "global_load_dwordx4 %3, %4, off offset:48 sc0 sc1\n\t"
      "s_waitcnt vmcnt(0)"
      : "=&v"(sp[0]), "=&v"(sp[1]), "=&v"(sp[2]), "=&v"(sp[3])
      : "v"(p) : "memory");
}

// 40 spike bytes (tail of the 232-wide k-split)
__device__ __forceinline__ void spk_load40(const unsigned char* p,
                                           u32x4& a, u32x4& b, u32x2& c) {
  asm volatile(
      "global_load_dwordx4 %0, %3, off sc0 sc1\n\t"
      "global_load_dwordx4 %1, %3, off offset:16 sc0 sc1\n\t"
      "global_load_dwordx2 %2, %3, off offset:32 sc0 sc1\n\t"
      "s_waitcnt vmcnt(0)"
      : "=&v"(a), "=&v"(b), "=&v"(c) : "v"(p) : "memory");
}

// coherent 4-byte spike store (write-through to Infinity Cache)
__device__ __forceinline__ void spk_store4(unsigned char* p, unsigned v) {
  asm volatile("global_store_dword %0, %1, off sc0 sc1"
               :: "v"(p), "v"(v) : "memory");
}

// acc[j] += sum over 16 k of spike * w; weights are normal cached loads
__device__ __forceinline__ void fmac16(float acc[HT], u32x4 sw,
                                       const float* __restrict__ wr) {
  float s[16];
  cvt4(sw[0], s); cvt4(sw[1], s + 4); cvt4(sw[2], s + 8); cvt4(sw[3], s + 12);
#pragma unroll
  for (int j = 0; j < HT; ++j) {
    const float4* w4 = (const float4*)(wr + (size_t)j * Hn);
    float4 wa = w4[0], wb = w4[1], wc = w4[2], wd = w4[3];
    acc[j] = fmaf(wa.x, s[0],  acc[j]);
    acc[j] = fmaf(wa.y, s[1],  acc[j]);
    acc[j] = fmaf(wa.z, s[2],  acc[j]);
    acc[j] = fmaf(wa.w, s[3],  acc[j]);
    acc[j] = fmaf(wb.x, s[4],  acc[j]);
    acc[j] = fmaf(wb.y, s[5],  acc[j]);
    acc[j] = fmaf(wb.z, s[6],  acc[j]);
    acc[j] = fmaf(wb.w, s[7],  acc[j]);
    acc[j] = fmaf(wc.x, s[8],  acc[j]);
    acc[j] = fmaf(wc.y, s[9],  acc[j]);
    acc[j] = fmaf(wc.z, s[10], acc[j]);
    acc[j] = fmaf(wc.w, s[11], acc[j]);
    acc[j] = fmaf(wd.x, s[12], acc[j]);
    acc[j] = fmaf(wd.y, s[13], acc[j]);
    acc[j] = fmaf(wd.z, s[14], acc[j]);
    acc[j] = fmaf(wd.w, s[15], acc[j]);
  }
}

__device__ __forceinline__ void fmac8(float acc[HT], u32x2 sw,
                                      const float* __restrict__ wr) {
  float s[8];
  cvt4(sw[0], s); cvt4(sw[1], s + 4);
#pragma unroll
  for (int j = 0; j < HT; ++j) {
    const float4* w4 = (const float4*)(wr + (size_t)j * Hn);
    float4 wa = w4[0], wb = w4[1];
    acc[j] = fmaf(wa.x, s[0], acc[j]);
    acc[j] = fmaf(wa.y, s[1], acc[j]);
    acc[j] = fmaf(wa.z, s[2], acc[j]);
    acc[j] = fmaf(wa.w, s[3], acc[j]);
    acc[j] = fmaf(wb.x, s[4], acc[j]);
    acc[j] = fmaf(wb.y, s[5], acc[j]);
    acc[j] = fmaf(wb.z, s[6], acc[j]);
    acc[j] = fmaf(wb.w, s[7], acc[j]);
  }
}

// acc[j] += sum_{k in [k0,k1)} spike(b,k) * wrow[j*Hn + k]
__device__ __forceinline__ void accum_range(float acc[HT],
    const unsigned char* __restrict__ srow,
    const float* __restrict__ wrow, int k0, int k1) {
  int kc = k0;
  for (; kc + 64 <= k1; kc += 64) {
    u32x4 sp[4];
    spk_load64(srow + kc, sp);
#pragma unroll
    for (int c = 0; c < 4; ++c)
      fmac16(acc, sp[c], wrow + kc + c * 16);
  }
  if (kc < k1) {   // 40-wide tail (only the 232-wide split)
    u32x4 a, b; u32x2 c2;
    spk_load40(srow + kc, a, b, c2);
    fmac16(acc, a, wrow + kc);
    fmac16(acc, b, wrow + kc + 16);
    fmac8(acc, c2, wrow + kc + 32);
  }
}

// LIF (tau=2, v_th=1, hard reset) for 4 neurons; returns packed spike bytes
__device__ __forceinline__ unsigned lif_pack(float v[HT], const float a[HT]) {
  unsigned pack = 0;
#pragma unroll
  for (int j = 0; j < HT; ++j) {
    float vn = v[j] + (a[j] - v[j]) * 0.5f;
    bool sp = (vn >= 1.0f);
    v[j] = sp ? 0.0f : vn;
    pack |= (sp ? 1u : 0u) << (8 * j);
  }
  return pack;
}

__global__ void __launch_bounds__(1024, 4)
snn_coop(const float* __restrict__ x,
         const float* __restrict__ W1, const float* __restrict__ R1,
         const float* __restrict__ W2, const float* __restrict__ R2,
         const float* __restrict__ W3, const float* __restrict__ R3,
         unsigned char* __restrict__ sb,
         unsigned* __restrict__ bar,
         float* __restrict__ out)
{
  extern __shared__ float4 red[];   // [3][NKS-1][Bsz]

  const int tid = threadIdx.x;
  const int b   = tid & 255;                                  // batch
  const int ks  = __builtin_amdgcn_readfirstlane(tid >> 8);   // k-split 0..3
  const int h0  = blockIdx.x * HT;                            // uniform

  const int k0 = ks * 256;
  const int k1 = (ks == 3) ? Hn : (k0 + 256);   // 256/256/256/232

  const float* W1r = W1 + (size_t)h0 * Lf;
  const float* R1r = R1 + (size_t)h0 * Hn;
  const float* W2r = W2 + (size_t)h0 * Hn;
  const float* R2r = R2 + (size_t)h0 * Hn;
  const float* W3r = W3 + (size_t)h0 * Hn;
  const float* R3r = R3 + (size_t)h0 * Hn;

  float v1[HT], v2[HT], v3[HT];
#pragma unroll
  for (int j = 0; j < HT; ++j) { v1[j] = 0.f; v2[j] = 0.f; v3[j] = 0.f; }

  const float* xb = x + (size_t)b * (Lf * Tt); // x[b][l][t]

  // Diagonal pipeline: phase p -> L1@t=p, L2@t=p-1, L3@t=p-2.
  // Spike writes in phase p go to slot (p&1); reads from slot ((p-1)&1).
  for (int p = 0; p < Tt + 2; ++p) {
    const int srd = (p + 1) & 1;
    const int swr = p & 1;

    float a1[HT] = {0.f, 0.f, 0.f, 0.f};
    float a2[HT] = {0.f, 0.f, 0.f, 0.f};
    float a3[HT] = {0.f, 0.f, 0.f, 0.f};

    const bool l1on = (p < Tt);
    const bool l2on = (p >= 1) && (p <= Tt);
    const bool l3on = (p >= 2);

    if (l1on) {
      if (ks == 3) {   // feedforward x @ W1^T (k=14) on the lighter k-split
#pragma unroll
        for (int l = 0; l < Lf; ++l) {
          float xv = xb[(size_t)l * Tt + p];
#pragma unroll
          for (int j = 0; j < HT; ++j)
            a1[j] = fmaf(W1r[j * Lf + l], xv, a1[j]);
        }
      }
      accum_range(a1, sb + srow_off(srd, 0, b), R1r, k0, k1);  // c1 @ R1^T
    }
    if (l2on) {
      accum_range(a2, sb + srow_off(srd, 0, b), W2r, k0, k1);  // s1 @ W2^T
      accum_range(a2, sb + srow_off(srd, 1, b), R2r, k0, k1);  // c2 @ R2^T
    }
    if (l3on) {
      accum_range(a3, sb + srow_off(srd, 1, b), W3r, k0, k1);  // s2 @ W3^T
      accum_range(a3, sb + srow_off(srd, 2, b), R3r, k0, k1);  // c3 @ R3^T
    }

    if (ks != 0) {
      if (l1on) red[(0 * (NKS - 1) + ks - 1) * Bsz + b] = make_float4(a1[0], a1[1], a1[2], a1[3]);
      if (l2on) red[(1 * (NKS - 1) + ks - 1) * Bsz + b] = make_float4(a2[0], a2[1], a2[2], a2[3]);
      if (l3on) red[(2 * (NKS - 1) + ks - 1) * Bsz + b] = make_float4(a3[0], a3[1], a3[2], a3[3]);
    }
    __syncthreads();

    if (ks == 0) {
      if (l1on) {
#pragma unroll
        for (int q = 0; q < NKS - 1; ++q) {
          float4 r = red[(0 * (NKS - 1) + q) * Bsz + b];
          a1[0] += r.x; a1[1] += r.y; a1[2] += r.z; a1[3] += r.w;
        }
        spk_store4(sb + srow_off(swr, 0, b) + h0, lif_pack(v1, a1));
      }
      if (l2on) {
#pragma unroll
        for (int q = 0; q < NKS - 1; ++q) {
          float4 r = red[(1 * (NKS - 1) + q) * Bsz + b];
          a2[0] += r.x; a2[1] += r.y; a2[2] += r.z; a2[3] += r.w;
        }
        spk_store4(sb + srow_off(swr, 1, b) + h0, lif_pack(v2, a2));
      }
      if (l3on) {
#pragma unroll
        for (int q = 0; q < NKS - 1; ++q) {
          float4 r = red[(2 * (NKS - 1) + q) * Bsz + b];
          a3[0] += r.x; a3[1] += r.y; a3[2] += r.z; a3[3] += r.w;
        }
        spk_store4(sb + srow_off(swr, 2, b) + h0, lif_pack(v3, a3));
      }
    }

    // ---- fence-free grid barrier (no cache invalidation!) ----
    // release: this wave's coherent stores/loads complete
    asm volatile("s_waitcnt vmcnt(0)" ::: "memory");
    __syncthreads();  // all waves of the block done (incl. red[] reads above)
    if (tid == 0) {
      __hip_atomic_fetch_add(bar, 1u, __ATOMIC_RELAXED, __HIP_MEMORY_SCOPE_AGENT);
      const unsigned tgt = (unsigned)(p + 1) * NBLK;
      while (__hip_atomic_load(bar, __ATOMIC_RELAXED, __HIP_MEMORY_SCOPE_AGENT) < tgt) {}
    }
    __syncthreads();
  }

  // Output: exp(final v3); [B][H] row-major, float4 store
  if (ks == 0) {
    float4 o = make_float4(expf(v3[0]), expf(v3[1]), expf(v3[2]), expf(v3[3]));
    *(float4*)(out + (size_t)b * Hn + h0) = o;
  }
}

extern "C" void kernel_launch(void* const* d_in, const int* in_sizes, int n_in,
                              void* d_out, int out_size, void* d_ws, size_t ws_size,
                              hipStream_t stream) {
  const float* x  = (const float*)d_in[0];
  const float* W1 = (const float*)d_in[1];
  const float* R1 = (const float*)d_in[2];
  const float* W2 = (const float*)d_in[3];
  const float* R2 = (const float*)d_in[4];
  const float* W3 = (const float*)d_in[5];
  const float* R3 = (const float*)d_in[6];
  float* out = (float*)d_out;

  unsigned char* sbytes = (unsigned char*)d_ws;
  unsigned* bar = (unsigned*)((char*)d_ws + SB_BYTES);

  // allow >64KB dynamic LDS (host-side attribute; graph-capture safe)
  hipFuncSetAttribute((const void*)snn_coop,
                      hipFuncAttributeMaxDynamicSharedMemorySize,
                      (int)SMEM_BYTES);

  // zero spike slots + barrier counter (deterministic per launch/replay)
  hipMemsetAsync(d_ws, 0, SB_BYTES + 64, stream);

  void* args[] = { (void*)&x, (void*)&W1, (void*)&R1, (void*)&W2, (void*)&R2,
                   (void*)&W3, (void*)&R3, (void*)&sbytes, (void*)&bar,
                   (void*)&out };
  // cooperative launch guarantees all 250 blocks co-resident (our barrier
  // replaces grid.sync, so no fence-induced cache invalidation occurs)
  hipLaunchCooperativeKernel((const void*)snn_coop, dim3(NBLK), dim3(1024),
                             args, SMEM_BYTES, stream);
}